// Round 4
// baseline (91.333 us; speedup 1.0000x reference)
//
#include <hip/hip_runtime.h>
#include <cstdint>

typedef float f32x4 __attribute__((ext_vector_type(4)));
typedef __fp16 f16;
typedef f16 f16x2 __attribute__((ext_vector_type(2)));
typedef f16 f16x8 __attribute__((ext_vector_type(8)));

constexpr int Bv = 32;      // batch rows (M)
constexpr int Hv = 4096;    // hidden (K1, N2)
constexpr int Iv = 2048;    // intermediate
constexpr int N1 = 4096;    // 2*I

// ---------------------------------------------------------------------------
// fp4 e2m1 word (8 nibbles, LSB-first along K) -> 8 exact f16 values in
// PERMUTED fragment order: (n0,n2),(n4,n6),(n1,n3),(n5,n7).
// Legal because MFMA contracts A(q,j) with B(q,j): any within-lane j->k
// permutation is fine as long as A uses the SAME order (packA / act layout).
// f16 magnitude high-byte LUT (idx 0-7): 00,38,3C,3E,40,42,44,46; low byte 0.
// ---------------------------------------------------------------------------
__device__ __forceinline__ f16x8 dec8h(uint32_t w) {
  uint32_t lo = w & 0x07070707u;          // mag idx n0,n2,n4,n6
  uint32_t hi = (w >> 4) & 0x07070707u;   // mag idx n1,n3,n5,n7
  uint32_t e = __builtin_amdgcn_perm(0x46444240u, 0x3E3C3800u, lo)
             | ((w & 0x08080808u) << 4);  // high bytes + sign (even nibbles)
  uint32_t o = __builtin_amdgcn_perm(0x46444240u, 0x3E3C3800u, hi)
             | (w & 0x80808080u);         // high bytes + sign (odd nibbles)
  union { uint32_t u[4]; f16x8 v; } r;
  // zero-interleave: second perm source is 0 -> selector bytes 0x00 give 0x00
  r.u[0] = __builtin_amdgcn_perm(e, 0u, 0x05000400u);  // f16(n0), f16(n2)
  r.u[1] = __builtin_amdgcn_perm(e, 0u, 0x07000600u);  // f16(n4), f16(n6)
  r.u[2] = __builtin_amdgcn_perm(o, 0u, 0x05000400u);  // f16(n1), f16(n3)
  r.u[3] = __builtin_amdgcn_perm(o, 0u, 0x07000600u);  // f16(n5), f16(n7)
  return r.v;
}

// 8 consecutive f32 (originally fp16 -> exact) -> f16x8 in the same permuted
// fragment order (k-offsets 0,2,4,6,1,3,5,7).
__device__ __forceinline__ f16x8 packA(const float* p) {
  f32x4 a = *(const f32x4*)p;
  f32x4 b = *(const f32x4*)(p + 4);
  union { f16x2 h[4]; f16x8 v; } r;
  r.h[0] = __builtin_amdgcn_cvt_pkrtz(a[0], a[2]);
  r.h[1] = __builtin_amdgcn_cvt_pkrtz(b[0], b[2]);
  r.h[2] = __builtin_amdgcn_cvt_pkrtz(a[1], a[3]);
  r.h[3] = __builtin_amdgcn_cvt_pkrtz(a[1 + 2], a[3]);  // placeholder (fixed below)
  // NOTE: the line above is replaced by the correct packing just under —
  // kept structure identical to avoid accidental reorder.
  r.h[2] = __builtin_amdgcn_cvt_pkrtz(a[1], a[3]);
  r.h[3] = __builtin_amdgcn_cvt_pkrtz(b[1], b[3]);
  return r.v;
}

// ---------------------------------------------------------------------------
// K1+K2 fused: act[32][2048] (f16, K3 fragment order) =
//   swiglu( x @ dequant(W_gu) ).
// 256 wgs x 1024 thr (1 wg/CU). wg b owns PAIRED columns: gate b*8..b*8+7
// and up 2048+b*8..+7, packed into one 16-wide MFMA B-fragment via per-lane
// column select (r<8 -> gate, r>=8 -> up). Full K=4096: 16 waves x K=256
// (two 128-wide scale groups per wave, separate accumulators, exact f32
// scale combine). 16-way LDS reduce -> shfl_xor(8) pairs gate/up in-wave ->
// SwiGLU in-register -> direct f16 act store in permuted fragment order.
// Deletes the k_swiglu launch and the 2 MiB hp round-trip.
// ---------------------------------------------------------------------------
__global__ __launch_bounds__(1024, 4) void k_gus(
    const float* __restrict__ x, const uint32_t* __restrict__ wp,
    const float* __restrict__ sc, f16* __restrict__ act) {
  __shared__ float lds[16 * 512];
  const int b = blockIdx.x;                // 0..255: 8-col gate/up pair tile
  const int wid = threadIdx.x >> 6, lane = threadIdx.x & 63;
  const int q = lane >> 4, r = lane & 15;
  const int ncol = (r < 8) ? (b * 8 + r) : (Iv + b * 8 + (r - 8));

  const float* px0 = x + r * Hv + wid * 256 + q * 8;   // rows r / r+16
  const float* px1 = px0 + 16 * Hv;
  const uint32_t* pb = wp + (size_t)(wid * 32 + q) * N1 + ncol;
  const float* ps = sc + (size_t)(wid * 2) * N1 + ncol;

  f32x4 a0g0 = {0,0,0,0}, a1g0 = {0,0,0,0};  // rows 0-15 / 16-31, group 0
  f32x4 a0g1 = {0,0,0,0}, a1g1 = {0,0,0,0};  // group 1 (K +128)
  #pragma unroll
  for (int st = 0; st < 4; ++st) {           // scale group 0: K 0..127
    f16x8 A0 = packA(px0 + st * 32);
    f16x8 A1 = packA(px1 + st * 32);
    f16x8 B  = dec8h(pb[(size_t)(st * 4) * N1]);
    a0g0 = __builtin_amdgcn_mfma_f32_16x16x32_f16(A0, B, a0g0, 0, 0, 0);
    a1g0 = __builtin_amdgcn_mfma_f32_16x16x32_f16(A1, B, a1g0, 0, 0, 0);
  }
  #pragma unroll
  for (int st = 0; st < 4; ++st) {           // scale group 1: K 128..255
    f16x8 A0 = packA(px0 + 128 + st * 32);
    f16x8 A1 = packA(px1 + 128 + st * 32);
    f16x8 B  = dec8h(pb[(size_t)(16 + st * 4) * N1]);
    a0g1 = __builtin_amdgcn_mfma_f32_16x16x32_f16(A0, B, a0g1, 0, 0, 0);
    a1g1 = __builtin_amdgcn_mfma_f32_16x16x32_f16(A1, B, a1g1, 0, 0, 0);
  }
  const float s0 = ps[0], s1 = ps[N1];
  float* my = lds + wid * 512;
  #pragma unroll
  for (int j = 0; j < 4; ++j) {
    const int rw = q * 4 + j;
    my[rw * 16 + r]        = s0 * a0g0[j] + s1 * a0g1[j];
    my[(16 + rw) * 16 + r] = s0 * a1g0[j] + s1 * a1g1[j];
  }
  __syncthreads();
  const int i = threadIdx.x;
  if (i < 512) {                             // 512 outputs (32 rows x 16 cols)
    float sum = 0.f;
    #pragma unroll
    for (int w = 0; w < 16; ++w) sum += lds[w * 512 + i];
    const float peer = __shfl_xor(sum, 8, 64);   // gate <-> up partner
    const int c = i & 15;
    if (c < 8) {
      const float g = sum, u = peer;
      const float av = g / (1.0f + __expf(-g)) * u;
      // store in K3's permuted fragment order within this 8-chunk
      const int pos = (c & 1) ? (4 + (c >> 1)) : (c >> 1);
      act[(i >> 4) * Iv + b * 8 + pos] = (f16)av;
    }
  }
}

// ---------------------------------------------------------------------------
// K3: out f32 [32][4096] = act[32,2048] @ dequant(W_down).
// 256 wgs x 1024 thr: wg = 16-col tile x full K(2048). f16 MFMA path:
// A = f16 act (16B loads, already fragment-ordered), B = exact f16 dequant.
// ---------------------------------------------------------------------------
__global__ __launch_bounds__(1024, 4) void k_down(
    const f16* __restrict__ act, const uint32_t* __restrict__ wp,
    const float* __restrict__ sc, float* __restrict__ out) {
  __shared__ float lds[16 * 512];
  const int n0 = blockIdx.x * 16;
  const int wid = threadIdx.x >> 6, lane = threadIdx.x & 63;
  const int q = lane >> 4, r = lane & 15;
  const int n = n0 + r;

  const int koff = wid * 128 + q * 8;
  const f16* pa0 = act + r * Iv + koff;
  const f16* pa1 = act + (r + 16) * Iv + koff;
  const uint32_t* pb = wp + (size_t)(wid * 16 + q) * Hv + n;

  f32x4 t0 = {0,0,0,0}, t1 = {0,0,0,0};
  #pragma unroll
  for (int st = 0; st < 4; ++st) {
    f16x8 A0 = *(const f16x8*)(pa0 + st * 32);
    f16x8 A1 = *(const f16x8*)(pa1 + st * 32);
    f16x8 B  = dec8h(pb[(size_t)st * 4 * Hv]);
    t0 = __builtin_amdgcn_mfma_f32_16x16x32_f16(A0, B, t0, 0, 0, 0);
    t1 = __builtin_amdgcn_mfma_f32_16x16x32_f16(A1, B, t1, 0, 0, 0);
  }
  const float sv = sc[wid * Hv + n];
  float* my = lds + wid * 512;
  #pragma unroll
  for (int j = 0; j < 4; ++j) {
    const int rw = q * 4 + j;
    my[rw * 16 + r]        = sv * t0[j];
    my[(16 + rw) * 16 + r] = sv * t1[j];
  }
  __syncthreads();
  const int i = threadIdx.x;
  if (i < 512) {                            // 512 outputs (32x16)
    float sum = 0.f;
    #pragma unroll
    for (int w = 0; w < 16; ++w) sum += lds[w * 512 + i];
    out[(i >> 4) * N1 + n0 + (i & 15)] = sum;
  }
}

// ---------------------------------------------------------------------------
extern "C" void kernel_launch(void* const* d_in, const int* in_sizes, int n_in,
                              void* d_out, int out_size, void* d_ws, size_t ws_size,
                              hipStream_t stream) {
  // Harness promotes float16 tensors to float32. x, scales, out are f32.
  const float*    x   = (const float*)d_in[0];      // f32 [32,4096]
  const uint32_t* gup = (const uint32_t*)d_in[1];   // [512,4096] packed fp4
  const float*    gus = (const float*)d_in[2];      // f32 [32,4096]
  const uint32_t* dnp = (const uint32_t*)d_in[3];   // [256,4096] packed fp4
  const float*    dns = (const float*)d_in[4];      // f32 [16,4096]

  f16* act = (f16*)d_ws;                            // [32][2048] f16 = 128 KiB

  k_gus <<<256, 1024, 0, stream>>>(x, gup, gus, act);
  k_down<<<256, 1024, 0, stream>>>(act, dnp, dns, (float*)d_out);
}

// Round 5
// 85.936 us; speedup vs baseline: 1.0628x; 1.0628x over previous
//
#include <hip/hip_runtime.h>
#include <cstdint>

typedef float f32x4 __attribute__((ext_vector_type(4)));
typedef __fp16 f16;
typedef f16 f16x2 __attribute__((ext_vector_type(2)));
typedef f16 f16x8 __attribute__((ext_vector_type(8)));

constexpr int Bv = 32;      // batch rows (M)
constexpr int Hv = 4096;    // hidden (K1, N2)
constexpr int Iv = 2048;    // intermediate
constexpr int N1 = 4096;    // 2*I

// ---------------------------------------------------------------------------
// fp4 e2m1 word (8 nibbles, LSB-first along K) -> 8 exact f16 values in
// PERMUTED fragment order: (n0,n2),(n4,n6),(n1,n3),(n5,n7).
// Legal because MFMA contracts A(q,j) with B(q,j): any within-lane j->k
// permutation is fine as long as A uses the SAME order (packA / act layout).
// f16 magnitude high-byte LUT (idx 0-7): 00,38,3C,3E,40,42,44,46; low byte 0.
// ---------------------------------------------------------------------------
__device__ __forceinline__ f16x8 dec8h(uint32_t w) {
  uint32_t lo = w & 0x07070707u;          // mag idx n0,n2,n4,n6
  uint32_t hi = (w >> 4) & 0x07070707u;   // mag idx n1,n3,n5,n7
  uint32_t e = __builtin_amdgcn_perm(0x46444240u, 0x3E3C3800u, lo)
             | ((w & 0x08080808u) << 4);  // high bytes + sign (even nibbles)
  uint32_t o = __builtin_amdgcn_perm(0x46444240u, 0x3E3C3800u, hi)
             | (w & 0x80808080u);         // high bytes + sign (odd nibbles)
  union { uint32_t u[4]; f16x8 v; } r;
  // zero-interleave: second perm source is 0 -> selector bytes 0x00 give 0x00
  r.u[0] = __builtin_amdgcn_perm(e, 0u, 0x05000400u);  // f16(n0), f16(n2)
  r.u[1] = __builtin_amdgcn_perm(e, 0u, 0x07000600u);  // f16(n4), f16(n6)
  r.u[2] = __builtin_amdgcn_perm(o, 0u, 0x05000400u);  // f16(n1), f16(n3)
  r.u[3] = __builtin_amdgcn_perm(o, 0u, 0x07000600u);  // f16(n5), f16(n7)
  return r.v;
}

// 8 consecutive f32 (originally fp16 -> exact) -> f16x8 in the same permuted
// fragment order (k-offsets 0,2,4,6,1,3,5,7).
__device__ __forceinline__ f16x8 packA(const float* p) {
  f32x4 a = *(const f32x4*)p;
  f32x4 b = *(const f32x4*)(p + 4);
  union { f16x2 h[4]; f16x8 v; } r;
  r.h[0] = __builtin_amdgcn_cvt_pkrtz(a[0], a[2]);
  r.h[1] = __builtin_amdgcn_cvt_pkrtz(b[0], b[2]);
  r.h[2] = __builtin_amdgcn_cvt_pkrtz(a[1], a[3]);
  r.h[3] = __builtin_amdgcn_cvt_pkrtz(b[1], b[3]);
  return r.v;
}

// ---------------------------------------------------------------------------
// K1+K2 fused (M-split): act[32][2048] f16 = swiglu( x @ dequant(W_gu) ).
// 256 wgs x 1024 thr (1 wg/CU). wg = (mh, ct): 16 rows (mh half of M) x
// 16 gate cols (ct*16..) + their 16 paired up cols (Iv+ct*16..), FULL K=4096.
// 16 waves: wave wid = K slice [wid*256, wid*256+256) = scale groups
// 2*wid, 2*wid+1 (separate f32 accumulators, exact scale combine).
// Inner loop keeps R3's ratio: 1 packA + 2 dec8h per 2 MFMAs (A shared
// across gate and up fragments). 16-way LDS reduce over full K -> SwiGLU
// in epilogue -> direct f16 act store in K3's permuted fragment order.
// Deletes the k_swiglu launch and the 2 MiB hp round-trip vs R3.
// ---------------------------------------------------------------------------
__global__ __launch_bounds__(1024, 4) void k_gus(
    const float* __restrict__ x, const uint32_t* __restrict__ wp,
    const float* __restrict__ sc, f16* __restrict__ act) {
  __shared__ float lds[16 * 512];          // 16 waves x (16 rows x 32 cols)
  const int mh = blockIdx.x & 1;           // M half: rows mh*16..mh*16+15
  const int ct = blockIdx.x >> 1;          // 0..127: 16-col gate/up pair tile
  const int wid = threadIdx.x >> 6, lane = threadIdx.x & 63;
  const int q = lane >> 4, r = lane & 15;
  const int cg = ct * 16 + r;              // gate col; up col = Iv + cg

  const float* px = x + (size_t)(mh * 16 + r) * Hv + wid * 256 + q * 8;
  const uint32_t* pbA = wp + (size_t)(wid * 32 + q) * N1 + cg;       // gate
  const uint32_t* pbB = pbA + Iv;                                    // up
  const float* ps = sc + (size_t)(wid * 2) * N1 + cg;

  f32x4 ga0 = {0,0,0,0}, ua0 = {0,0,0,0};  // scale group 2*wid
  f32x4 ga1 = {0,0,0,0}, ua1 = {0,0,0,0};  // scale group 2*wid+1
  #pragma unroll
  for (int st = 0; st < 4; ++st) {         // K 0..127 of this wave's slice
    f16x8 A  = packA(px + st * 32);
    f16x8 BA = dec8h(pbA[(size_t)(st * 4) * N1]);
    f16x8 BB = dec8h(pbB[(size_t)(st * 4) * N1]);
    ga0 = __builtin_amdgcn_mfma_f32_16x16x32_f16(A, BA, ga0, 0, 0, 0);
    ua0 = __builtin_amdgcn_mfma_f32_16x16x32_f16(A, BB, ua0, 0, 0, 0);
  }
  #pragma unroll
  for (int st = 0; st < 4; ++st) {         // K 128..255 of this wave's slice
    f16x8 A  = packA(px + 128 + st * 32);
    f16x8 BA = dec8h(pbA[(size_t)(16 + st * 4) * N1]);
    f16x8 BB = dec8h(pbB[(size_t)(16 + st * 4) * N1]);
    ga1 = __builtin_amdgcn_mfma_f32_16x16x32_f16(A, BA, ga1, 0, 0, 0);
    ua1 = __builtin_amdgcn_mfma_f32_16x16x32_f16(A, BB, ua1, 0, 0, 0);
  }
  const float sg0 = ps[0],  sg1 = ps[N1];        // gate scales (groups 0/1)
  const float su0 = ps[Iv], su1 = ps[N1 + Iv];   // up scales
  float* my = lds + wid * 512;
  #pragma unroll
  for (int j = 0; j < 4; ++j) {
    const int rw = q * 4 + j;              // row within 16-row tile
    my[rw * 32 + r]      = sg0 * ga0[j] + sg1 * ga1[j];
    my[rw * 32 + 16 + r] = su0 * ua0[j] + su1 * ua1[j];
  }
  __syncthreads();
  const int i = threadIdx.x;
  if (i < 256) {                           // 16 rows x 16 cols outputs
    const int row = i >> 4, c = i & 15;
    float g = 0.f, u = 0.f;
    #pragma unroll
    for (int w = 0; w < 16; ++w) {
      g += lds[w * 512 + row * 32 + c];
      u += lds[w * 512 + row * 32 + 16 + c];
    }
    const float av = g / (1.0f + __expf(-g)) * u;
    // store in K3's permuted fragment order within the aligned 8-chunk
    const int d = c & 7;
    const int pos = (d & 1) ? (4 + (d >> 1)) : (d >> 1);
    act[(size_t)(mh * 16 + row) * Iv + ct * 16 + (c & 8) + pos] = (f16)av;
  }
}

// ---------------------------------------------------------------------------
// K3: out f32 [32][4096] = act[32,2048] @ dequant(W_down).
// 256 wgs x 1024 thr: wg = 16-col tile x full K(2048). f16 MFMA path:
// A = f16 act (16B loads, already fragment-ordered), B = exact f16 dequant.
// ---------------------------------------------------------------------------
__global__ __launch_bounds__(1024, 4) void k_down(
    const f16* __restrict__ act, const uint32_t* __restrict__ wp,
    const float* __restrict__ sc, float* __restrict__ out) {
  __shared__ float lds[16 * 512];
  const int n0 = blockIdx.x * 16;
  const int wid = threadIdx.x >> 6, lane = threadIdx.x & 63;
  const int q = lane >> 4, r = lane & 15;
  const int n = n0 + r;

  const int koff = wid * 128 + q * 8;
  const f16* pa0 = act + r * Iv + koff;
  const f16* pa1 = act + (r + 16) * Iv + koff;
  const uint32_t* pb = wp + (size_t)(wid * 16 + q) * Hv + n;

  f32x4 t0 = {0,0,0,0}, t1 = {0,0,0,0};
  #pragma unroll
  for (int st = 0; st < 4; ++st) {
    f16x8 A0 = *(const f16x8*)(pa0 + st * 32);
    f16x8 A1 = *(const f16x8*)(pa1 + st * 32);
    f16x8 B  = dec8h(pb[(size_t)st * 4 * Hv]);
    t0 = __builtin_amdgcn_mfma_f32_16x16x32_f16(A0, B, t0, 0, 0, 0);
    t1 = __builtin_amdgcn_mfma_f32_16x16x32_f16(A1, B, t1, 0, 0, 0);
  }
  const float sv = sc[wid * Hv + n];
  float* my = lds + wid * 512;
  #pragma unroll
  for (int j = 0; j < 4; ++j) {
    const int rw = q * 4 + j;
    my[rw * 16 + r]        = sv * t0[j];
    my[(16 + rw) * 16 + r] = sv * t1[j];
  }
  __syncthreads();
  const int i = threadIdx.x;
  if (i < 512) {                            // 512 outputs (32x16)
    float sum = 0.f;
    #pragma unroll
    for (int w = 0; w < 16; ++w) sum += lds[w * 512 + i];
    out[(i >> 4) * N1 + n0 + (i & 15)] = sum;
  }
}

// ---------------------------------------------------------------------------
extern "C" void kernel_launch(void* const* d_in, const int* in_sizes, int n_in,
                              void* d_out, int out_size, void* d_ws, size_t ws_size,
                              hipStream_t stream) {
  // Harness promotes float16 tensors to float32. x, scales, out are f32.
  const float*    x   = (const float*)d_in[0];      // f32 [32,4096]
  const uint32_t* gup = (const uint32_t*)d_in[1];   // [512,4096] packed fp4
  const float*    gus = (const float*)d_in[2];      // f32 [32,4096]
  const uint32_t* dnp = (const uint32_t*)d_in[3];   // [256,4096] packed fp4
  const float*    dns = (const float*)d_in[4];      // f32 [16,4096]

  f16* act = (f16*)d_ws;                            // [32][2048] f16 = 128 KiB

  k_gus <<<256, 1024, 0, stream>>>(x, gup, gus, act);
  k_down<<<256, 1024, 0, stream>>>(act, dnp, dns, (float*)d_out);
}